// Round 11
// baseline (129.859 us; speedup 1.0000x reference)
//
#include <hip/hip_runtime.h>
#include <hip/hip_bf16.h>

#define N_NODES 10000
#define N_EDGES 640000
#define F_IN 128
#define H1 64
#define H2 32
#define N_CLASSES 16

#define NB 128          // radix buckets (bucket 127 always empty: 9999/79=126)
#define NUSED 127       // buckets actually used
#define NPB 79          // nodes per bucket (79*127 = 10033 >= 10000)
#define STAGE_C 64      // per-block per-bucket staging capacity (mean 16, 12 sigma)
#define SLOT 6144       // per-bucket srcU region (mean ~5039, 15 sigma)
#define IDX_CAP 4096    // per-block LDS index staging capacity (gathers)
#define PART_BLOCKS 313 // ceil(160000/512)

typedef unsigned short ushortT;

// bf16 pair unpack: element j0 = low 16 bits (little-endian), j0+1 = high
__device__ __forceinline__ float bf_lo(unsigned u) {
    u <<= 16; float f; __builtin_memcpy(&f, &u, 4); return f;
}
__device__ __forceinline__ float bf_hi(unsigned u) {
    u &= 0xffff0000u; float f; __builtin_memcpy(&f, &u, 4); return f;
}
__device__ __forceinline__ unsigned bf_pack(float a, float b) {
    __hip_bfloat16 ha = __float2bfloat16(a), hb = __float2bfloat16(b);
    unsigned short ua, ub;
    __builtin_memcpy(&ua, &ha, 2); __builtin_memcpy(&ub, &hb, 2);
    return (unsigned)ua | ((unsigned)ub << 16);
}

// ---------- dispatch 1: edge partition (blocks 0..312) + GEMM1 (313..937) ----------
// part: pack src(14b) | local_dst(7b)<<14; per-block deterministic output —
//       blockCnt[blk][bucket] plain stores + partBuf[blk][bucket][64]. NO atomics,
//       NO init required (every slot written).
// gemm: h1b = bf16(x @ W1), UNSCALED — dinv applied in-place by k_bsort.
__global__ void __launch_bounds__(256) k_part_gemm1(const int* __restrict__ src,
                                                    const int* __restrict__ dst,
                                                    ushortT* __restrict__ blockCnt,
                                                    int* __restrict__ partBuf,
                                                    const float* __restrict__ x,
                                                    const float* __restrict__ W1,
                                                    __hip_bfloat16* __restrict__ h1b,
                                                    const float* __restrict__ bfc,
                                                    float* __restrict__ out) {
    __shared__ __align__(16) char pool[40960];  // union: part 33KB / gemm 40KB
    int t = threadIdx.x;
    if (blockIdx.x < PART_BLOCKS) {
        int* cnt   = (int*)pool;           // 128
        int* stage = (int*)(pool + 512);   // 128*64 ints (32 KB)
        if (t < NB) cnt[t] = 0;
        __syncthreads();
        const int4* src4 = (const int4*)src;
        const int4* dst4 = (const int4*)dst;
#pragma unroll
        for (int k = 0; k < 2; ++k) {
            int i4 = blockIdx.x * 512 + k * 256 + t;
            if (i4 < N_EDGES / 4) {
                int4 s = src4[i4];
                int4 d = dst4[i4];
                int b, l, p;
                b = d.x / NPB; l = d.x - b * NPB; p = atomicAdd(&cnt[b], 1); stage[b * STAGE_C + p] = s.x | (l << 14);
                b = d.y / NPB; l = d.y - b * NPB; p = atomicAdd(&cnt[b], 1); stage[b * STAGE_C + p] = s.y | (l << 14);
                b = d.z / NPB; l = d.z - b * NPB; p = atomicAdd(&cnt[b], 1); stage[b * STAGE_C + p] = s.z | (l << 14);
                b = d.w / NPB; l = d.w - b * NPB; p = atomicAdd(&cnt[b], 1); stage[b * STAGE_C + p] = s.w | (l << 14);
            }
        }
        __syncthreads();
        if (t < NB) blockCnt[blockIdx.x * NB + t] = (ushortT)cnt[t];
        for (int i = t; i < NB * STAGE_C; i += 256) {
            int b = i >> 6;            // / STAGE_C
            int k = i & (STAGE_C - 1);
            if (k < cnt[b]) partBuf[blockIdx.x * (NB * STAGE_C) + i] = stage[i];
        }
    } else {
        int gb = blockIdx.x - PART_BLOCKS;   // 0..624
        float* w1s = (float*)pool;           // [128][64] = 32 KB
        float* xs  = (float*)(pool + 32768); // [16][128] = 8 KB
        int node0 = gb * 16;                 // 625*16 = 10000 exact
        const float4* W14 = (const float4*)W1;
        float4* w1s4 = (float4*)w1s;
#pragma unroll
        for (int i = 0; i < 8; ++i) w1s4[i * 256 + t] = W14[i * 256 + t];
        const float4* x4 = (const float4*)(x + (long)node0 * F_IN);
        float4* xs4 = (float4*)xs;
#pragma unroll
        for (int i = 0; i < 2; ++i) xs4[i * 256 + t] = x4[i * 256 + t];
        if (gb == 0 && t < N_CLASSES) out[t] = bfc[t];  // seed output with bias
        __syncthreads();
        int j = t & 63;
        int q = t >> 6;       // wave id 0..3
        int r0 = q * 4;
        float acc0 = 0.f, acc1 = 0.f, acc2 = 0.f, acc3 = 0.f;
#pragma unroll 4
        for (int k = 0; k < F_IN; ++k) {
            float w = w1s[k * H1 + j];
            acc0 += xs[(r0 + 0) * F_IN + k] * w;
            acc1 += xs[(r0 + 1) * F_IN + k] * w;
            acc2 += xs[(r0 + 2) * F_IN + k] * w;
            acc3 += xs[(r0 + 3) * F_IN + k] * w;
        }
        int v0 = node0 + r0;
        h1b[(v0 + 0) * H1 + j] = __float2bfloat16(acc0);
        h1b[(v0 + 1) * H1 + j] = __float2bfloat16(acc1);
        h1b[(v0 + 2) * H1 + j] = __float2bfloat16(acc2);
        h1b[(v0 + 3) * H1 + j] = __float2bfloat16(acc3);
    }
}

// ---------- dispatch 2: per-bucket counting sort + dinv + in-place h1 scale ----------
// 127 blocks, one per bucket. Bucket b owns srcU region [b*SLOT, b*SLOT+total_b).
// rowStart/rowEnd per node (separate arrays: inter-bucket gaps stay outside all
// node ranges). Entries staged to LDS once; placed from LDS.
__global__ void __launch_bounds__(512) k_bsort(const ushortT* __restrict__ blockCnt,
                                               const int* __restrict__ partBuf,
                                               ushortT* __restrict__ srcU,
                                               int* __restrict__ rowStart,
                                               int* __restrict__ rowEnd,
                                               float* __restrict__ dinv,
                                               __hip_bfloat16* __restrict__ h1b) {
    __shared__ ushortT cntL[PART_BLOCKS];
    __shared__ int stageL[SLOT];     // 24 KB
    __shared__ int ldeg[NPB];
    __shared__ int lpre[NPB];
    __shared__ int cur[NPB];
    __shared__ float sdv[NPB];
    __shared__ int nStage;
    int t = threadIdx.x;
    int b = blockIdx.x;
    for (int i = t; i < PART_BLOCKS; i += 512) cntL[i] = blockCnt[i * NB + b];
    if (t < NPB) ldeg[t] = 0;
    if (t == 0) nStage = 0;
    __syncthreads();
    // sweep all part-blocks' chunks for this bucket; stage entries into LDS
    for (int i = t; i < PART_BLOCKS * STAGE_C; i += 512) {
        int blk = i >> 6, k = i & (STAGE_C - 1);
        if (k < (int)cntL[blk]) {
            int p = partBuf[blk * (NB * STAGE_C) + b * STAGE_C + k];
            int pos = atomicAdd(&nStage, 1);
            stageL[pos] = p;
            atomicAdd(&ldeg[p >> 14], 1);
        }
    }
    __syncthreads();
    int nodeBase = b * NPB;
    int nNodes = N_NODES - nodeBase;
    if (nNodes > NPB) nNodes = NPB;   // b=126 -> 46
    if (t == 0) {
        int run = 0;
        for (int i = 0; i < nNodes; ++i) { lpre[i] = run; run += ldeg[i]; }
    }
    __syncthreads();
    int base = b * SLOT;
    if (t < nNodes) {
        int v = nodeBase + t;
        rowStart[v] = base + lpre[t];
        rowEnd[v]   = base + lpre[t] + ldeg[t];
        cur[t] = lpre[t];
        float dv_ = rsqrtf((float)ldeg[t] + 1.0f);
        dinv[v] = dv_;
        sdv[t] = dv_;
    }
    __syncthreads();
    int total = nStage;
    for (int i = t; i < total; i += 512) {
        int p = stageL[i];
        int pos = atomicAdd(&cur[p >> 14], 1);
        srcU[base + pos] = (ushortT)(p & 16383);
    }
    // scale this bucket's h1 rows by dinv, in place (bf16 pairs as u32)
    unsigned* h1u = (unsigned*)h1b;
    for (int i = t; i < nNodes * 32; i += 512) {
        int ln = i >> 5, p = i & 31;
        int v = nodeBase + ln;
        unsigned u = h1u[v * 32 + p];
        float d = sdv[ln];
        h1u[v * 32 + p] = bf_pack(bf_lo(u) * d, bf_hi(u) * d);
    }
}

// ---------- dispatch 3: gather layer1 (CSR, bf16x2, LDS-staged u16 idx) + ReLU + GEMM2 ----------
// 1250 blocks x 256 threads = 8 nodes x 32 lanes; lane owns feature pair.
__global__ void __launch_bounds__(256) k_gather1_gemm2(const __hip_bfloat16* __restrict__ h1b,
                                const int* __restrict__ rowStart,
                                const int* __restrict__ rowEnd,
                                const ushortT* __restrict__ srcU,
                                const float* __restrict__ dinv,
                                const float* __restrict__ b1,
                                const float* __restrict__ W2,
                                __hip_bfloat16* __restrict__ h2b) {
    __shared__ float h1s[8][H1];       // 2 KB
    __shared__ ushortT idxs[IDX_CAP];  // 8 KB
    __shared__ int sRange[2];
    int t = threadIdx.x;
    int n  = t >> 5;        // node slot 0..7
    int fp = t & 31;        // feature pair
    int v = blockIdx.x * 8 + n;   // 1250*8 = 10000 exact
    if (t == 0) { sRange[0] = rowStart[blockIdx.x * 8]; sRange[1] = rowEnd[blockIdx.x * 8 + 7]; }
    __syncthreads();
    int rs0 = sRange[0];
    int cnt0 = sRange[1] - rs0;
    bool useLds = (cnt0 <= IDX_CAP);
    if (useLds) for (int i = t; i < cnt0; i += 256) idxs[i] = srcU[rs0 + i];
    float dv_ = dinv[v];
    int rs = rowStart[v], re = rowEnd[v];
    const unsigned* h1u = (const unsigned*)h1b;
    unsigned su = h1u[v * 32 + fp];          // self-loop term
    float fx = bf_lo(su), fy = bf_hi(su);
    float x0 = 0.f, y0 = 0.f, x1 = 0.f, y1 = 0.f;
    float x2 = 0.f, y2 = 0.f, x3 = 0.f, y3 = 0.f;
    __syncthreads();
    if (useLds) {
        int le = rs - rs0, lend = re - rs0;
        for (; le + 4 <= lend; le += 4) {
            int i0 = idxs[le],     i1 = idxs[le + 1];
            int i2 = idxs[le + 2], i3 = idxs[le + 3];
            unsigned u0 = h1u[i0 * 32 + fp];
            unsigned u1 = h1u[i1 * 32 + fp];
            unsigned u2 = h1u[i2 * 32 + fp];
            unsigned u3 = h1u[i3 * 32 + fp];
            x0 += bf_lo(u0); y0 += bf_hi(u0);
            x1 += bf_lo(u1); y1 += bf_hi(u1);
            x2 += bf_lo(u2); y2 += bf_hi(u2);
            x3 += bf_lo(u3); y3 += bf_hi(u3);
        }
        for (; le < lend; ++le) {
            unsigned u = h1u[idxs[le] * 32 + fp];
            fx += bf_lo(u); fy += bf_hi(u);
        }
    } else {  // fallback: direct global reads (degree-skew safety)
        for (int e = rs; e < re; ++e) {
            unsigned u = h1u[(int)srcU[e] * 32 + fp];
            fx += bf_lo(u); fy += bf_hi(u);
        }
    }
    fx += (x0 + x1) + (x2 + x3);
    fy += (y0 + y1) + (y2 + y3);
    ((float2*)h1s[n])[fp] = make_float2(fmaxf(dv_ * fx + b1[fp * 2], 0.f),
                                        fmaxf(dv_ * fy + b1[fp * 2 + 1], 0.f));
    __syncthreads();
    // GEMM2: thread = (node n, output j=fp in [0,32))
    float acc = 0.f;
#pragma unroll
    for (int kk = 0; kk < H1; ++kk)
        acc += h1s[n][kk] * W2[kk * H2 + fp];
    h2b[v * H2 + fp] = __float2bfloat16(acc * dv_);  // pre-scaled
}

// ---------- dispatch 4: gather layer2 + ReLU + partial mean + partial FC -> out ----------
// 625 blocks x 256 threads = 16 nodes x 16 lanes. out pre-seeded with bfc;
// each block atomically adds its partial (mean @ Wfc) — linear, so exact.
__global__ void __launch_bounds__(256) k_gather2_out(const __hip_bfloat16* __restrict__ h2b,
                               const int* __restrict__ rowStart,
                               const int* __restrict__ rowEnd,
                               const ushortT* __restrict__ srcU,
                               const float* __restrict__ dinv,
                               const float* __restrict__ b2,
                               const float* __restrict__ Wfc,
                               float* __restrict__ out) {
    __shared__ float red[16][H2];      // 2 KB
    __shared__ ushortT idxs[IDX_CAP];  // 8 KB
    __shared__ int sRange[2];
    __shared__ float gs[H2];
    int t = threadIdx.x;
    int n  = t >> 4;        // node slot 0..15
    int fp = t & 15;        // feature pair of H2
    int v = blockIdx.x * 16 + n;   // 625*16 = 10000 exact
    if (t == 0) { sRange[0] = rowStart[blockIdx.x * 16]; sRange[1] = rowEnd[blockIdx.x * 16 + 15]; }
    __syncthreads();
    int rs0 = sRange[0];
    int cnt0 = sRange[1] - rs0;
    bool useLds = (cnt0 <= IDX_CAP);
    if (useLds) for (int i = t; i < cnt0; i += 256) idxs[i] = srcU[rs0 + i];
    float dv_ = dinv[v];
    int rs = rowStart[v], re = rowEnd[v];
    const unsigned* h2u = (const unsigned*)h2b;
    unsigned su = h2u[v * 16 + fp];          // self-loop term
    float fx = bf_lo(su), fy = bf_hi(su);
    float x0 = 0.f, y0 = 0.f, x1 = 0.f, y1 = 0.f;
    float x2 = 0.f, y2 = 0.f, x3 = 0.f, y3 = 0.f;
    __syncthreads();
    if (useLds) {
        int le = rs - rs0, lend = re - rs0;
        for (; le + 4 <= lend; le += 4) {
            int i0 = idxs[le],     i1 = idxs[le + 1];
            int i2 = idxs[le + 2], i3 = idxs[le + 3];
            unsigned u0 = h2u[i0 * 16 + fp];
            unsigned u1 = h2u[i1 * 16 + fp];
            unsigned u2 = h2u[i2 * 16 + fp];
            unsigned u3 = h2u[i3 * 16 + fp];
            x0 += bf_lo(u0); y0 += bf_hi(u0);
            x1 += bf_lo(u1); y1 += bf_hi(u1);
            x2 += bf_lo(u2); y2 += bf_hi(u2);
            x3 += bf_lo(u3); y3 += bf_hi(u3);
        }
        for (; le < lend; ++le) {
            unsigned u = h2u[idxs[le] * 16 + fp];
            fx += bf_lo(u); fy += bf_hi(u);
        }
    } else {
        for (int e = rs; e < re; ++e) {
            unsigned u = h2u[(int)srcU[e] * 16 + fp];
            fx += bf_lo(u); fy += bf_hi(u);
        }
    }
    fx += (x0 + x1) + (x2 + x3);
    fy += (y0 + y1) + (y2 + y3);
    ((float2*)red[n])[fp] = make_float2(fmaxf(dv_ * fx + b2[fp * 2], 0.f),
                                        fmaxf(dv_ * fy + b2[fp * 2 + 1], 0.f));
    __syncthreads();
    if (t < H2) {
        float s = 0.f;
#pragma unroll
        for (int r = 0; r < 16; ++r) s += red[r][t];
        gs[t] = s;
    }
    __syncthreads();
    if (t < N_CLASSES) {
        float acc = 0.f;
#pragma unroll
        for (int j = 0; j < H2; ++j)
            acc += gs[j] * Wfc[j * N_CLASSES + t];
        atomicAdd(&out[t], acc * (1.0f / (float)N_NODES));
    }
}

extern "C" void kernel_launch(void* const* d_in, const int* in_sizes, int n_in,
                              void* d_out, int out_size, void* d_ws, size_t ws_size,
                              hipStream_t stream) {
    const float* x   = (const float*)d_in[0];
    const float* W1  = (const float*)d_in[1];
    const float* b1  = (const float*)d_in[2];
    const float* W2  = (const float*)d_in[3];
    const float* b2  = (const float*)d_in[4];
    const float* Wfc = (const float*)d_in[5];
    const float* bfc = (const float*)d_in[6];
    const int* edge = (const int*)d_in[7];
    const int* srcI = edge;              // edge_index[0]
    const int* dstI = edge + N_EDGES;    // edge_index[1]
    float* out = (float*)d_out;

    // workspace layout (~14 MB of the 256 MiB ws); no init required anywhere.
    char* ws = (char*)d_ws;
    ushortT* blockCnt = (ushortT*)(ws + 0);        // 313*128 u16 -> 80128 B
    int*     rowStart = (int*)    (ws + 81920);    // 10000 ints
    int*     rowEnd   = (int*)    (ws + 122880);   // 10000 ints
    float*   dinv     = (float*)  (ws + 163840);   // 10000 f
    ushortT* srcU     = (ushortT*)(ws + 204800);   // 127*6144 u16 -> 1560576 B
    int*     partBuf  = (int*)    (ws + 1765376);  // 313*128*64 ints -> 10.26 MB
    __hip_bfloat16* h1b = (__hip_bfloat16*)(ws + 12021760);  // 640000 bf16
    __hip_bfloat16* h2b = (__hip_bfloat16*)(ws + 13301760);  // 320000 bf16

    k_part_gemm1<<<PART_BLOCKS + N_NODES / 16, 256, 0, stream>>>(
        srcI, dstI, blockCnt, partBuf, x, W1, h1b, bfc, out);
    k_bsort<<<NUSED, 512, 0, stream>>>(blockCnt, partBuf, srcU, rowStart, rowEnd,
                                       dinv, h1b);
    k_gather1_gemm2<<<N_NODES / 8, 256, 0, stream>>>(h1b, rowStart, rowEnd, srcU,
                                                     dinv, b1, W2, h2b);
    k_gather2_out<<<N_NODES / 16, 256, 0, stream>>>(h2b, rowStart, rowEnd, srcU,
                                                    dinv, b2, Wfc, out);
}

// Round 12
// 125.258 us; speedup vs baseline: 1.0367x; 1.0367x over previous
//
#include <hip/hip_runtime.h>
#include <hip/hip_bf16.h>

#define N_NODES 10000
#define N_EDGES 640000
#define F_IN 128
#define H1 64
#define H2 32
#define N_CLASSES 16

#define NB 128          // radix buckets
#define NPB 79          // nodes per bucket (79*128 = 10112 >= 10000)
#define STAGE_C 64      // per-bucket LDS staging capacity (mean 16/blk)
#define SLOT 6144       // per-bucket partBuf capacity (mean ~5056)
#define IDX_CAP 4096    // per-block LDS index staging capacity
#define PART_BLOCKS 313 // ceil(160000/512)

typedef unsigned short ushortT;

// bf16 pair unpack: element j0 = low 16 bits (little-endian), j0+1 = high
__device__ __forceinline__ float bf_lo(unsigned u) {
    u <<= 16; float f; __builtin_memcpy(&f, &u, 4); return f;
}
__device__ __forceinline__ float bf_hi(unsigned u) {
    u &= 0xffff0000u; float f; __builtin_memcpy(&f, &u, 4); return f;
}
__device__ __forceinline__ unsigned bf_pack(float a, float b) {
    __hip_bfloat16 ha = __float2bfloat16(a), hb = __float2bfloat16(b);
    unsigned short ua, ub;
    __builtin_memcpy(&ua, &ha, 2); __builtin_memcpy(&ub, &hb, 2);
    return (unsigned)ua | ((unsigned)ub << 16);
}

// ---------- fused dispatch 2: edge partition (blocks 0..312) + GEMM1 (313..937) ----------
// part: pack src(14b) | local_dst(7b)<<14 into 128 dst-range buckets (dense
//       per-bucket partBuf regions via global atomic cursor).
// gemm: h1b = bf16(x @ W1), UNSCALED — dinv applied in-place by k_bsort.
__global__ void __launch_bounds__(256) k_part_gemm1(const int* __restrict__ src,
                                                    const int* __restrict__ dst,
                                                    int* __restrict__ bucketCursor,
                                                    int* __restrict__ partBuf,
                                                    const float* __restrict__ x,
                                                    const float* __restrict__ W1,
                                                    __hip_bfloat16* __restrict__ h1b,
                                                    const float* __restrict__ bfc,
                                                    float* __restrict__ out) {
    __shared__ __align__(16) char pool[40960];  // union: part 33KB / gemm 40KB
    int t = threadIdx.x;
    if (blockIdx.x < PART_BLOCKS) {
        int* cnt   = (int*)pool;           // 128
        int* gbase = (int*)(pool + 512);   // 128
        int* stage = (int*)(pool + 1024);  // 128*64 ints (32 KB)
        if (t < NB) cnt[t] = 0;
        __syncthreads();
        const int4* src4 = (const int4*)src;
        const int4* dst4 = (const int4*)dst;
#pragma unroll
        for (int k = 0; k < 2; ++k) {
            int i4 = blockIdx.x * 512 + k * 256 + t;
            if (i4 < N_EDGES / 4) {
                int4 s = src4[i4];
                int4 d = dst4[i4];
                int b, l, p;
                b = d.x / NPB; l = d.x - b * NPB; p = atomicAdd(&cnt[b], 1); stage[b * STAGE_C + p] = s.x | (l << 14);
                b = d.y / NPB; l = d.y - b * NPB; p = atomicAdd(&cnt[b], 1); stage[b * STAGE_C + p] = s.y | (l << 14);
                b = d.z / NPB; l = d.z - b * NPB; p = atomicAdd(&cnt[b], 1); stage[b * STAGE_C + p] = s.z | (l << 14);
                b = d.w / NPB; l = d.w - b * NPB; p = atomicAdd(&cnt[b], 1); stage[b * STAGE_C + p] = s.w | (l << 14);
            }
        }
        __syncthreads();
        if (t < NB) gbase[t] = atomicAdd(&bucketCursor[t], cnt[t]);
        __syncthreads();
        for (int i = t; i < NB * STAGE_C; i += 256) {
            int b = i >> 6;            // / STAGE_C
            int k = i & (STAGE_C - 1);
            if (k < cnt[b]) partBuf[b * SLOT + gbase[b] + k] = stage[i];
        }
    } else {
        int gb = blockIdx.x - PART_BLOCKS;   // 0..624
        float* w1s = (float*)pool;           // [128][64] = 32 KB
        float* xs  = (float*)(pool + 32768); // [16][128] = 8 KB
        int node0 = gb * 16;                 // 625*16 = 10000 exact
        const float4* W14 = (const float4*)W1;
        float4* w1s4 = (float4*)w1s;
#pragma unroll
        for (int i = 0; i < 8; ++i) w1s4[i * 256 + t] = W14[i * 256 + t];
        const float4* x4 = (const float4*)(x + (long)node0 * F_IN);
        float4* xs4 = (float4*)xs;
#pragma unroll
        for (int i = 0; i < 2; ++i) xs4[i * 256 + t] = x4[i * 256 + t];
        if (gb == 0 && t < N_CLASSES) out[t] = bfc[t];  // seed output with bias
        __syncthreads();
        int j = t & 63;
        int q = t >> 6;       // wave id 0..3
        int r0 = q * 4;
        float acc0 = 0.f, acc1 = 0.f, acc2 = 0.f, acc3 = 0.f;
#pragma unroll 4
        for (int k = 0; k < F_IN; ++k) {
            float w = w1s[k * H1 + j];
            acc0 += xs[(r0 + 0) * F_IN + k] * w;
            acc1 += xs[(r0 + 1) * F_IN + k] * w;
            acc2 += xs[(r0 + 2) * F_IN + k] * w;
            acc3 += xs[(r0 + 3) * F_IN + k] * w;
        }
        int v0 = node0 + r0;
        h1b[(v0 + 0) * H1 + j] = __float2bfloat16(acc0);
        h1b[(v0 + 1) * H1 + j] = __float2bfloat16(acc1);
        h1b[(v0 + 2) * H1 + j] = __float2bfloat16(acc2);
        h1b[(v0 + 3) * H1 + j] = __float2bfloat16(acc3);
    }
}

// ---------- dispatch 3: per-bucket counting sort + dinv + in-place h1 scale ----------
__global__ void __launch_bounds__(512) k_bsort(const int* __restrict__ bucketCursor,
                                               const int* __restrict__ partBuf,
                                               ushortT* __restrict__ srcU,
                                               int* __restrict__ rowStart,
                                               float* __restrict__ dinv,
                                               __hip_bfloat16* __restrict__ h1b) {
    __shared__ int sc[NB];
    __shared__ int ldeg[NPB];
    __shared__ int lpre[NPB];
    __shared__ int cur[NPB];
    __shared__ float sdv[NPB];
    int t = threadIdx.x;
    int b = blockIdx.x;
    if (b == 0 && t == 0) rowStart[N_NODES] = N_EDGES;
    // redundant per-block scan of all 128 bucket totals
    if (t < NB) sc[t] = bucketCursor[t];
    __syncthreads();
    for (int off = 1; off < NB; off <<= 1) {
        int v = (t >= off && t < NB) ? sc[t - off] : 0;
        __syncthreads();
        if (t < NB) sc[t] += v;
        __syncthreads();
    }
    int cnt = bucketCursor[b];
    int base = sc[b] - cnt;  // exclusive prefix
    int nodeBase = b * NPB;
    int nNodes = N_NODES - nodeBase;
    if (nNodes <= 0) return;  // bucket 127 is empty
    if (nNodes > NPB) nNodes = NPB;
    if (t < NPB) ldeg[t] = 0;
    __syncthreads();
    // count local degrees
    for (int i = t; i < cnt; i += 512) {
        int p = partBuf[b * SLOT + i];
        atomicAdd(&ldeg[p >> 14], 1);
    }
    __syncthreads();
    if (t == 0) {
        int run = 0;
        for (int i = 0; i < nNodes; ++i) { lpre[i] = run; run += ldeg[i]; }
    }
    __syncthreads();
    if (t < nNodes) {
        int v = nodeBase + t;
        rowStart[v] = base + lpre[t];
        cur[t] = lpre[t];
        float dv_ = rsqrtf((float)ldeg[t] + 1.0f);
        dinv[v] = dv_;
        sdv[t] = dv_;
    }
    __syncthreads();
    // place
    for (int i = t; i < cnt; i += 512) {
        int p = partBuf[b * SLOT + i];
        int pos = atomicAdd(&cur[p >> 14], 1);
        srcU[base + pos] = (ushortT)(p & 16383);
    }
    // scale this bucket's h1 rows by dinv, in place (bf16 pairs as u32)
    unsigned* h1u = (unsigned*)h1b;
    for (int i = t; i < nNodes * 32; i += 512) {
        int ln = i >> 5, p = i & 31;
        int v = nodeBase + ln;
        unsigned u = h1u[v * 32 + p];
        float d = sdv[ln];
        h1u[v * 32 + p] = bf_pack(bf_lo(u) * d, bf_hi(u) * d);
    }
}

// ---------- dispatch 4: gather layer1 (CSR, bf16x2, LDS-staged u16 idx) + ReLU + GEMM2 ----------
// 1250 blocks x 256 threads = 8 nodes x 32 lanes; lane owns feature pair.
__global__ void __launch_bounds__(256) k_gather1_gemm2(const __hip_bfloat16* __restrict__ h1b,
                                const int* __restrict__ rowStart,
                                const ushortT* __restrict__ srcU,
                                const float* __restrict__ dinv,
                                const float* __restrict__ b1,
                                const float* __restrict__ W2,
                                __hip_bfloat16* __restrict__ h2b) {
    __shared__ float h1s[8][H1];       // 2 KB
    __shared__ ushortT idxs[IDX_CAP];  // 8 KB
    __shared__ int sRange[2];
    int t = threadIdx.x;
    int n  = t >> 5;        // node slot 0..7
    int fp = t & 31;        // feature pair
    int v = blockIdx.x * 8 + n;   // 1250*8 = 10000 exact
    if (t == 0) { sRange[0] = rowStart[blockIdx.x * 8]; sRange[1] = rowStart[blockIdx.x * 8 + 8]; }
    __syncthreads();
    int rs0 = sRange[0];
    int cnt0 = sRange[1] - rs0;
    bool useLds = (cnt0 <= IDX_CAP);
    if (useLds) for (int i = t; i < cnt0; i += 256) idxs[i] = srcU[rs0 + i];
    float dv_ = dinv[v];
    int rs = rowStart[v], re = rowStart[v + 1];
    const unsigned* h1u = (const unsigned*)h1b;
    unsigned su = h1u[v * 32 + fp];          // self-loop term
    float fx = bf_lo(su), fy = bf_hi(su);
    float x0 = 0.f, y0 = 0.f, x1 = 0.f, y1 = 0.f;
    float x2 = 0.f, y2 = 0.f, x3 = 0.f, y3 = 0.f;
    __syncthreads();
    if (useLds) {
        int le = rs - rs0, lend = re - rs0;
        for (; le + 4 <= lend; le += 4) {
            int i0 = idxs[le],     i1 = idxs[le + 1];
            int i2 = idxs[le + 2], i3 = idxs[le + 3];
            unsigned u0 = h1u[i0 * 32 + fp];
            unsigned u1 = h1u[i1 * 32 + fp];
            unsigned u2 = h1u[i2 * 32 + fp];
            unsigned u3 = h1u[i3 * 32 + fp];
            x0 += bf_lo(u0); y0 += bf_hi(u0);
            x1 += bf_lo(u1); y1 += bf_hi(u1);
            x2 += bf_lo(u2); y2 += bf_hi(u2);
            x3 += bf_lo(u3); y3 += bf_hi(u3);
        }
        for (; le < lend; ++le) {
            unsigned u = h1u[idxs[le] * 32 + fp];
            fx += bf_lo(u); fy += bf_hi(u);
        }
    } else {  // fallback: direct global reads (degree-skew safety, ~never taken)
        for (int e = rs; e < re; ++e) {
            unsigned u = h1u[(int)srcU[e] * 32 + fp];
            fx += bf_lo(u); fy += bf_hi(u);
        }
    }
    fx += (x0 + x1) + (x2 + x3);
    fy += (y0 + y1) + (y2 + y3);
    ((float2*)h1s[n])[fp] = make_float2(fmaxf(dv_ * fx + b1[fp * 2], 0.f),
                                        fmaxf(dv_ * fy + b1[fp * 2 + 1], 0.f));
    __syncthreads();
    // GEMM2: thread = (node n, output j=fp in [0,32))
    float acc = 0.f;
#pragma unroll
    for (int kk = 0; kk < H1; ++kk)
        acc += h1s[n][kk] * W2[kk * H2 + fp];
    h2b[v * H2 + fp] = __float2bfloat16(acc * dv_);  // pre-scaled
}

// ---------- dispatch 5: gather layer2 + ReLU + partial mean + partial FC -> out ----------
// 625 blocks x 256 threads = 16 nodes x 16 lanes. out pre-seeded with bfc;
// each block atomically adds its partial (mean @ Wfc) — linear, so exact.
__global__ void __launch_bounds__(256) k_gather2_out(const __hip_bfloat16* __restrict__ h2b,
                               const int* __restrict__ rowStart,
                               const ushortT* __restrict__ srcU,
                               const float* __restrict__ dinv,
                               const float* __restrict__ b2,
                               const float* __restrict__ Wfc,
                               float* __restrict__ out) {
    __shared__ float red[16][H2];      // 2 KB
    __shared__ ushortT idxs[IDX_CAP];  // 8 KB
    __shared__ int sRange[2];
    __shared__ float gs[H2];
    int t = threadIdx.x;
    int n  = t >> 4;        // node slot 0..15
    int fp = t & 15;        // feature pair of H2
    int v = blockIdx.x * 16 + n;   // 625*16 = 10000 exact
    if (t == 0) { sRange[0] = rowStart[blockIdx.x * 16]; sRange[1] = rowStart[blockIdx.x * 16 + 16]; }
    __syncthreads();
    int rs0 = sRange[0];
    int cnt0 = sRange[1] - rs0;
    bool useLds = (cnt0 <= IDX_CAP);
    if (useLds) for (int i = t; i < cnt0; i += 256) idxs[i] = srcU[rs0 + i];
    float dv_ = dinv[v];
    int rs = rowStart[v], re = rowStart[v + 1];
    const unsigned* h2u = (const unsigned*)h2b;
    unsigned su = h2u[v * 16 + fp];          // self-loop term
    float fx = bf_lo(su), fy = bf_hi(su);
    float x0 = 0.f, y0 = 0.f, x1 = 0.f, y1 = 0.f;
    float x2 = 0.f, y2 = 0.f, x3 = 0.f, y3 = 0.f;
    __syncthreads();
    if (useLds) {
        int le = rs - rs0, lend = re - rs0;
        for (; le + 4 <= lend; le += 4) {
            int i0 = idxs[le],     i1 = idxs[le + 1];
            int i2 = idxs[le + 2], i3 = idxs[le + 3];
            unsigned u0 = h2u[i0 * 16 + fp];
            unsigned u1 = h2u[i1 * 16 + fp];
            unsigned u2 = h2u[i2 * 16 + fp];
            unsigned u3 = h2u[i3 * 16 + fp];
            x0 += bf_lo(u0); y0 += bf_hi(u0);
            x1 += bf_lo(u1); y1 += bf_hi(u1);
            x2 += bf_lo(u2); y2 += bf_hi(u2);
            x3 += bf_lo(u3); y3 += bf_hi(u3);
        }
        for (; le < lend; ++le) {
            unsigned u = h2u[idxs[le] * 16 + fp];
            fx += bf_lo(u); fy += bf_hi(u);
        }
    } else {
        for (int e = rs; e < re; ++e) {
            unsigned u = h2u[(int)srcU[e] * 16 + fp];
            fx += bf_lo(u); fy += bf_hi(u);
        }
    }
    fx += (x0 + x1) + (x2 + x3);
    fy += (y0 + y1) + (y2 + y3);
    ((float2*)red[n])[fp] = make_float2(fmaxf(dv_ * fx + b2[fp * 2], 0.f),
                                        fmaxf(dv_ * fy + b2[fp * 2 + 1], 0.f));
    __syncthreads();
    if (t < H2) {
        float s = 0.f;
#pragma unroll
        for (int r = 0; r < 16; ++r) s += red[r][t];
        gs[t] = s;
    }
    __syncthreads();
    if (t < N_CLASSES) {
        float acc = 0.f;
#pragma unroll
        for (int j = 0; j < H2; ++j)
            acc += gs[j] * Wfc[j * N_CLASSES + t];
        atomicAdd(&out[t], acc * (1.0f / (float)N_NODES));
    }
}

extern "C" void kernel_launch(void* const* d_in, const int* in_sizes, int n_in,
                              void* d_out, int out_size, void* d_ws, size_t ws_size,
                              hipStream_t stream) {
    const float* x   = (const float*)d_in[0];
    const float* W1  = (const float*)d_in[1];
    const float* b1  = (const float*)d_in[2];
    const float* W2  = (const float*)d_in[3];
    const float* b2  = (const float*)d_in[4];
    const float* Wfc = (const float*)d_in[5];
    const float* bfc = (const float*)d_in[6];
    const int* edge = (const int*)d_in[7];
    const int* srcI = edge;              // edge_index[0]
    const int* dstI = edge + N_EDGES;    // edge_index[1]
    float* out = (float*)d_out;

    // workspace layout (~6.4 MB of ws); only bucketCursor needs init.
    char* ws = (char*)d_ws;
    int*     bucketCursor = (int*)    (ws + 0);        // 128 ints
    float*   dinv         = (float*)  (ws + 1024);     // 10000 f
    int*     rowStart     = (int*)    (ws + 41984);    // 10001 ints
    ushortT* srcU         = (ushortT*)(ws + 82944);    // 640000 u16 -> ends 1362944
    int*     partBuf      = (int*)    (ws + 1363968);  // 128*6144 ints -> ends 4509696
    __hip_bfloat16* h1b   = (__hip_bfloat16*)(ws + 4509696);  // 640000 bf16 -> ends 5789696
    __hip_bfloat16* h2b   = (__hip_bfloat16*)(ws + 5789696);  // 320000 bf16 -> ends 6429696

    hipMemsetAsync(bucketCursor, 0, 512, stream);

    k_part_gemm1<<<PART_BLOCKS + N_NODES / 16, 256, 0, stream>>>(
        srcI, dstI, bucketCursor, partBuf, x, W1, h1b, bfc, out);
    k_bsort<<<NB, 512, 0, stream>>>(bucketCursor, partBuf, srcU, rowStart, dinv, h1b);
    k_gather1_gemm2<<<N_NODES / 8, 256, 0, stream>>>(h1b, rowStart, srcU,
                                                     dinv, b1, W2, h2b);
    k_gather2_out<<<N_NODES / 16, 256, 0, stream>>>(h2b, rowStart, srcU,
                                                    dinv, b2, Wfc, out);
}